// Round 1
// baseline (654.139 us; speedup 1.0000x reference)
//
#include <hip/hip_runtime.h>

// ---------------------------------------------------------------------------
// GCN (3 layers) + global mean pool + linear, fp32, MI355X.
// Trick: norm = dinv[src]*dinv[dst] factors, so we fold dinv into the matmul
// output (t'[i] = dinv[i] * h[i] W^T) and the edge aggregation becomes a pure
// unweighted CSR sum:  h_next[i] = relu(dinv[i]*(t'[i] + sum_{j->i} t'[j]) + b)
// ---------------------------------------------------------------------------

__global__ __launch_bounds__(256) void init_kernel(int* __restrict__ cnt,
                                                   float* __restrict__ psum,
                                                   float* __restrict__ pcnt,
                                                   int n, int pb64, int pb) {
    int idx = blockIdx.x * blockDim.x + threadIdx.x;
    if (idx < n)    cnt[idx]  = 0;
    if (idx < pb64) psum[idx] = 0.0f;
    if (idx < pb)   pcnt[idx] = 0.0f;
}

__global__ __launch_bounds__(256) void count_kernel(const int* __restrict__ dst,
                                                    int* __restrict__ cnt, int e) {
    int idx = blockIdx.x * blockDim.x + threadIdx.x;
    if (idx < e) atomicAdd(&cnt[dst[idx]], 1);
}

__global__ __launch_bounds__(256) void dinv_kernel(const int* __restrict__ cnt,
                                                   float* __restrict__ dinv, int n) {
    int idx = blockIdx.x * blockDim.x + threadIdx.x;
    if (idx < n) dinv[idx] = rsqrtf((float)(cnt[idx] + 1));  // +1 = self loop
}

// Single-block exclusive scan of cnt -> rp; zeroes cnt for reuse as fill ctr.
__global__ __launch_bounds__(1024) void scan_kernel(int* __restrict__ cnt,
                                                    int* __restrict__ rp, int n) {
    __shared__ int partials[1024];
    int tid = threadIdx.x;
    int chunk = (n + 1023) >> 10;
    int beg = tid * chunk;
    int end = min(beg + chunk, n);
    int s = 0;
    for (int i = beg; i < end; ++i) s += cnt[i];
    partials[tid] = s;
    __syncthreads();
    for (int d = 1; d < 1024; d <<= 1) {
        int v   = partials[tid];
        int add = (tid >= d) ? partials[tid - d] : 0;
        __syncthreads();
        partials[tid] = v + add;
        __syncthreads();
    }
    int excl = (tid == 0) ? 0 : partials[tid - 1];
    for (int i = beg; i < end; ++i) {
        rp[i] = excl;
        excl += cnt[i];
        cnt[i] = 0;  // reuse as fill counter
    }
    if (tid == 1023) rp[n] = partials[1023];
}

__global__ __launch_bounds__(256) void fill_kernel(const int* __restrict__ src,
                                                   const int* __restrict__ dst,
                                                   const int* __restrict__ rp,
                                                   int* __restrict__ fill,
                                                   int* __restrict__ csr, int e) {
    int idx = blockIdx.x * blockDim.x + threadIdx.x;
    if (idx < e) {
        int d   = dst[idx];
        int pos = rp[d] + atomicAdd(&fill[d], 1);
        csr[pos] = src[idx];
    }
}

// t[i][o] = dinv[i] * sum_k h[i][k] * W[o][k]
// Block: 256 thr = 4 waves; 64 nodes/block. W row per lane in 16 float4 regs;
// 64 h-rows staged in LDS, read as broadcast float4.
__global__ __launch_bounds__(256) void mm_kernel(const float* __restrict__ h,
                                                 const float* __restrict__ W,
                                                 const float* __restrict__ dinv,
                                                 float* __restrict__ t, int n) {
    __shared__ float hs[64 * 64];
    int tid  = threadIdx.x;
    int lane = tid & 63;
    int wave = tid >> 6;
    int base = blockIdx.x * 64;

    float4 wreg[16];
    const float4* W4 = (const float4*)(W + lane * 64);
#pragma unroll
    for (int q = 0; q < 16; ++q) wreg[q] = W4[q];

    int nrows = min(64, n - base);
    const float4* h4  = (const float4*)(h + (size_t)base * 64);
    float4*       hs4 = (float4*)hs;
    for (int idx = tid; idx < nrows * 16; idx += 256) hs4[idx] = h4[idx];
    __syncthreads();

    for (int r = wave * 16; r < wave * 16 + 16; ++r) {
        int i = base + r;
        if (i >= n) break;
        const float4* row = (const float4*)(hs + r * 64);
        float acc = 0.0f;
#pragma unroll
        for (int q = 0; q < 16; ++q) {
            float4 hv = row[q];  // wave-uniform address -> LDS broadcast
            acc += hv.x * wreg[q].x + hv.y * wreg[q].y +
                   hv.z * wreg[q].z + hv.w * wreg[q].w;
        }
        t[i * 64 + lane] = acc * dinv[i];
    }
}

// One wave per node; lane = feature. 4-way unrolled gather-sum over in-edges.
__global__ __launch_bounds__(256) void agg_kernel(const float* __restrict__ t,
                                                  const int* __restrict__ rp,
                                                  const int* __restrict__ cs,
                                                  const float* __restrict__ dinv,
                                                  const float* __restrict__ bias,
                                                  float* __restrict__ hout, int n) {
    int gw   = (blockIdx.x * blockDim.x + threadIdx.x) >> 6;
    int lane = threadIdx.x & 63;
    if (gw >= n) return;
    int i   = gw;
    int beg = rp[i];
    int end = rp[i + 1];
    float acc0 = t[i * 64 + lane];  // self loop
    float acc1 = 0.f, acc2 = 0.f, acc3 = 0.f;
    int e = beg;
    for (; e + 4 <= end; e += 4) {
        int s0 = cs[e], s1 = cs[e + 1], s2 = cs[e + 2], s3 = cs[e + 3];
        acc0 += t[s0 * 64 + lane];
        acc1 += t[s1 * 64 + lane];
        acc2 += t[s2 * 64 + lane];
        acc3 += t[s3 * 64 + lane];
    }
    for (; e < end; ++e) acc1 += t[cs[e] * 64 + lane];
    float acc = (acc0 + acc1) + (acc2 + acc3);
    hout[i * 64 + lane] = fmaxf(fmaf(dinv[i], acc, bias[lane]), 0.0f);
}

__global__ __launch_bounds__(256) void pool_kernel(const float* __restrict__ h,
                                                   const int* __restrict__ batch,
                                                   float* __restrict__ psum,
                                                   float* __restrict__ pcnt, int n) {
    int idx = blockIdx.x * blockDim.x + threadIdx.x;
    if (idx >= n * 64) return;
    int i = idx >> 6;
    int f = idx & 63;
    int b = batch[i];
    atomicAdd(&psum[b * 64 + f], h[idx]);
    if (f == 0) atomicAdd(&pcnt[b], 1.0f);
}

__global__ __launch_bounds__(64) void final_kernel(const float* __restrict__ psum,
                                                   const float* __restrict__ pcnt,
                                                   const float* __restrict__ Wl,
                                                   const float* __restrict__ bl,
                                                   float* __restrict__ out, int nb) {
    __shared__ float prow[64];
    int b = blockIdx.x;
    int f = threadIdx.x;
    float c = fmaxf(pcnt[b], 1.0f);
    prow[f] = psum[b * 64 + f] / c;
    __syncthreads();
    if (f < 16) {
        float a = bl[f];
        const float* wr = Wl + f * 64;
#pragma unroll
        for (int k = 0; k < 64; ++k) a += prow[k] * wr[k];
        out[b * 16 + f] = a;
    }
}

extern "C" void kernel_launch(void* const* d_in, const int* in_sizes, int n_in,
                              void* d_out, int out_size, void* d_ws, size_t ws_size,
                              hipStream_t stream) {
    const float* x   = (const float*)d_in[0];
    const int*   ei  = (const int*)d_in[1];
    const int*  batch= (const int*)d_in[2];
    const float* W1  = (const float*)d_in[3];
    const float* b1  = (const float*)d_in[4];
    const float* W2  = (const float*)d_in[5];
    const float* b2  = (const float*)d_in[6];
    const float* W3  = (const float*)d_in[7];
    const float* b3  = (const float*)d_in[8];
    const float* Wl  = (const float*)d_in[9];
    const float* bl  = (const float*)d_in[10];
    float* out = (float*)d_out;

    const int n  = in_sizes[0] / 64;   // 50000 nodes
    const int e  = in_sizes[1] / 2;    // 1250000 edges
    const int nb = out_size / 16;      // 512 graphs

    const int* esrc = ei;
    const int* edst = ei + e;

    // Workspace carve (aligned to 256 B): ~31.5 MB total.
    char* p = (char*)d_ws;
    auto carve = [&](size_t bytes) {
        char* r = p;
        p += (bytes + 255) & ~(size_t)255;
        return r;
    };
    int*   cnt  = (int*)  carve((size_t)n * 4);          // degree, then fill ctr
    float* dinv = (float*)carve((size_t)n * 4);
    int*   rp   = (int*)  carve((size_t)(n + 1) * 4);
    int*   csr  = (int*)  carve((size_t)e * 4);
    float* bufA = (float*)carve((size_t)n * 64 * 4);
    float* bufB = (float*)carve((size_t)n * 64 * 4);
    float* psum = (float*)carve((size_t)nb * 64 * 4);
    float* pcnt = (float*)carve((size_t)nb * 4);

    dim3 blk(256);
    int gN = (n + 255) / 256;
    int gE = (e + 255) / 256;

    init_kernel<<<gN, blk, 0, stream>>>(cnt, psum, pcnt, n, nb * 64, nb);
    count_kernel<<<gE, blk, 0, stream>>>(edst, cnt, e);
    dinv_kernel<<<gN, blk, 0, stream>>>(cnt, dinv, n);
    scan_kernel<<<1, 1024, 0, stream>>>(cnt, rp, n);
    fill_kernel<<<gE, blk, 0, stream>>>(esrc, edst, rp, cnt, csr, e);

    int gMM  = (n + 63) / 64;
    int gAGG = (n + 3) / 4;  // 4 waves/block, one node per wave

    // Layer 1: x -> bufA -> bufB
    mm_kernel<<<gMM, blk, 0, stream>>>(x, W1, dinv, bufA, n);
    agg_kernel<<<gAGG, blk, 0, stream>>>(bufA, rp, csr, dinv, b1, bufB, n);
    // Layer 2: bufB -> bufA -> bufB
    mm_kernel<<<gMM, blk, 0, stream>>>(bufB, W2, dinv, bufA, n);
    agg_kernel<<<gAGG, blk, 0, stream>>>(bufA, rp, csr, dinv, b2, bufB, n);
    // Layer 3: bufB -> bufA -> bufB
    mm_kernel<<<gMM, blk, 0, stream>>>(bufB, W3, dinv, bufA, n);
    agg_kernel<<<gAGG, blk, 0, stream>>>(bufA, rp, csr, dinv, b3, bufB, n);

    pool_kernel<<<(n * 64 + 255) / 256, blk, 0, stream>>>(bufB, batch, psum, pcnt, n);
    final_kernel<<<nb, 64, 0, stream>>>(psum, pcnt, Wl, bl, out, nb);
}

// Round 2
// 474.561 us; speedup vs baseline: 1.3784x; 1.3784x over previous
//
#include <hip/hip_runtime.h>

// ---------------------------------------------------------------------------
// GCN (3 layers) + global mean pool + linear, fp32, MI355X.
// norm = dinv[src]*dinv[dst] factors -> fold dinv into matmul output
// (t'[i] = dinv[i] * h[i] W^T); aggregation is a pure unweighted CSR sum:
//   h_next[i] = relu(dinv[i]*(t'[i] + sum_{j->i} t'[j]) + b)
// R2: parallel 3-phase scan (was 110us single-block), dinv fused into scan3,
//     segment-aware pooling exploiting sorted batch.
// ---------------------------------------------------------------------------

__global__ __launch_bounds__(256) void init_kernel(int* __restrict__ cnt,
                                                   float* __restrict__ psum,
                                                   float* __restrict__ pcnt,
                                                   int n, int pb64, int pb) {
    int idx = blockIdx.x * blockDim.x + threadIdx.x;
    if (idx < n)    cnt[idx]  = 0;
    if (idx < pb64) psum[idx] = 0.0f;
    if (idx < pb)   pcnt[idx] = 0.0f;
}

__global__ __launch_bounds__(256) void count_kernel(const int* __restrict__ dst,
                                                    int* __restrict__ cnt, int e) {
    int idx = blockIdx.x * blockDim.x + threadIdx.x;
    if (idx < e) atomicAdd(&cnt[dst[idx]], 1);
}

// ---- 3-phase exclusive scan of cnt[0..n) -> rp, 1024 elements per block ----

__global__ __launch_bounds__(256) void scan1_kernel(const int* __restrict__ cnt,
                                                    int* __restrict__ bsum, int n) {
    int base = blockIdx.x * 1024;
    int tid  = threadIdx.x;
    int s = 0;
#pragma unroll
    for (int k = 0; k < 4; ++k) {
        int i = base + tid + k * 256;  // coalesced
        if (i < n) s += cnt[i];
    }
    for (int d = 32; d >= 1; d >>= 1) s += __shfl_down(s, d, 64);
    __shared__ int ws[4];
    if ((tid & 63) == 0) ws[tid >> 6] = s;
    __syncthreads();
    if (tid == 0) bsum[blockIdx.x] = ws[0] + ws[1] + ws[2] + ws[3];
}

// Single wave: exclusive scan of bsum[0..nbk), writes total to rp[n].
__global__ __launch_bounds__(64) void scan2_kernel(int* __restrict__ bsum,
                                                   int* __restrict__ rp,
                                                   int nbk, int n) {
    int tid = threadIdx.x;
    int carry = 0;
    for (int b0 = 0; b0 < nbk; b0 += 64) {
        int idx  = b0 + tid;
        int v    = (idx < nbk) ? bsum[idx] : 0;
        int orig = v;
        for (int d = 1; d < 64; d <<= 1) {
            int t = __shfl_up(v, d, 64);
            if (tid >= d) v += t;
        }
        if (idx < nbk) bsum[idx] = carry + v - orig;  // exclusive
        carry += __shfl(v, 63, 64);
    }
    if (tid == 0) rp[n] = carry;
}

// Per-block rescan with block offset; also computes dinv and zeroes cnt.
__global__ __launch_bounds__(256) void scan3_kernel(int* __restrict__ cnt,
                                                    const int* __restrict__ bsum,
                                                    int* __restrict__ rp,
                                                    float* __restrict__ dinv, int n) {
    int tid  = threadIdx.x;
    int lane = tid & 63;
    int wv   = tid >> 6;
    int i0   = blockIdx.x * 1024 + tid * 4;

    int4 c = make_int4(0, 0, 0, 0);
    if (i0 + 3 < n) {
        c = *(const int4*)(cnt + i0);
    } else {
        if (i0 + 0 < n) c.x = cnt[i0 + 0];
        if (i0 + 1 < n) c.y = cnt[i0 + 1];
        if (i0 + 2 < n) c.z = cnt[i0 + 2];
        if (i0 + 3 < n) c.w = cnt[i0 + 3];
    }
    int tsum = c.x + c.y + c.z + c.w;
    int v = tsum;
    for (int d = 1; d < 64; d <<= 1) {
        int t = __shfl_up(v, d, 64);
        if (lane >= d) v += t;
    }
    __shared__ int wsum[4];
    if (lane == 63) wsum[wv] = v;
    __syncthreads();
    int woff = 0;
    for (int w = 0; w < wv; ++w) woff += wsum[w];

    int p0 = bsum[blockIdx.x] + woff + (v - tsum);
    int p1 = p0 + c.x;
    int p2 = p1 + c.y;
    int p3 = p2 + c.z;
    if (i0 + 3 < n) {
        *(int4*)(rp + i0) = make_int4(p0, p1, p2, p3);
        *(float4*)(dinv + i0) =
            make_float4(rsqrtf((float)(c.x + 1)), rsqrtf((float)(c.y + 1)),
                        rsqrtf((float)(c.z + 1)), rsqrtf((float)(c.w + 1)));
        *(int4*)(cnt + i0) = make_int4(0, 0, 0, 0);
    } else {
        if (i0 + 0 < n) { rp[i0+0]=p0; dinv[i0+0]=rsqrtf((float)(c.x+1)); cnt[i0+0]=0; }
        if (i0 + 1 < n) { rp[i0+1]=p1; dinv[i0+1]=rsqrtf((float)(c.y+1)); cnt[i0+1]=0; }
        if (i0 + 2 < n) { rp[i0+2]=p2; dinv[i0+2]=rsqrtf((float)(c.z+1)); cnt[i0+2]=0; }
        if (i0 + 3 < n) { rp[i0+3]=p3; dinv[i0+3]=rsqrtf((float)(c.w+1)); cnt[i0+3]=0; }
    }
}

__global__ __launch_bounds__(256) void fill_kernel(const int* __restrict__ src,
                                                   const int* __restrict__ dst,
                                                   const int* __restrict__ rp,
                                                   int* __restrict__ fill,
                                                   int* __restrict__ csr, int e) {
    int idx = blockIdx.x * blockDim.x + threadIdx.x;
    if (idx < e) {
        int d   = dst[idx];
        int pos = rp[d] + atomicAdd(&fill[d], 1);
        csr[pos] = src[idx];
    }
}

// t[i][o] = dinv[i] * sum_k h[i][k] * W[o][k]
// 256 thr = 4 waves; 64 nodes/block. W row per lane in 16 float4 regs;
// 64 h-rows staged in LDS, read as broadcast float4.
__global__ __launch_bounds__(256) void mm_kernel(const float* __restrict__ h,
                                                 const float* __restrict__ W,
                                                 const float* __restrict__ dinv,
                                                 float* __restrict__ t, int n) {
    __shared__ float hs[64 * 64];
    int tid  = threadIdx.x;
    int lane = tid & 63;
    int wave = tid >> 6;
    int base = blockIdx.x * 64;

    float4 wreg[16];
    const float4* W4 = (const float4*)(W + lane * 64);
#pragma unroll
    for (int q = 0; q < 16; ++q) wreg[q] = W4[q];

    int nrows = min(64, n - base);
    const float4* h4  = (const float4*)(h + (size_t)base * 64);
    float4*       hs4 = (float4*)hs;
    for (int idx = tid; idx < nrows * 16; idx += 256) hs4[idx] = h4[idx];
    __syncthreads();

    for (int r = wave * 16; r < wave * 16 + 16; ++r) {
        int i = base + r;
        if (i >= n) break;
        const float4* row = (const float4*)(hs + r * 64);
        float acc = 0.0f;
#pragma unroll
        for (int q = 0; q < 16; ++q) {
            float4 hv = row[q];  // wave-uniform address -> LDS broadcast
            acc += hv.x * wreg[q].x + hv.y * wreg[q].y +
                   hv.z * wreg[q].z + hv.w * wreg[q].w;
        }
        t[i * 64 + lane] = acc * dinv[i];
    }
}

// One wave per node; lane = feature. 4-way unrolled gather-sum over in-edges.
__global__ __launch_bounds__(256) void agg_kernel(const float* __restrict__ t,
                                                  const int* __restrict__ rp,
                                                  const int* __restrict__ cs,
                                                  const float* __restrict__ dinv,
                                                  const float* __restrict__ bias,
                                                  float* __restrict__ hout, int n) {
    int gw   = (blockIdx.x * blockDim.x + threadIdx.x) >> 6;
    int lane = threadIdx.x & 63;
    if (gw >= n) return;
    int i   = gw;
    int beg = rp[i];
    int end = rp[i + 1];
    float acc0 = t[i * 64 + lane];  // self loop
    float acc1 = 0.f, acc2 = 0.f, acc3 = 0.f;
    int e = beg;
    for (; e + 4 <= end; e += 4) {
        int s0 = cs[e], s1 = cs[e + 1], s2 = cs[e + 2], s3 = cs[e + 3];
        acc0 += t[s0 * 64 + lane];
        acc1 += t[s1 * 64 + lane];
        acc2 += t[s2 * 64 + lane];
        acc3 += t[s3 * 64 + lane];
    }
    for (; e < end; ++e) acc1 += t[cs[e] * 64 + lane];
    float acc = (acc0 + acc1) + (acc2 + acc3);
    hout[i * 64 + lane] = fmaxf(fmaf(dinv[i], acc, bias[lane]), 0.0f);
}

// Sorted batch -> segment accumulate in registers, flush atomics on change.
// One wave handles 16 consecutive nodes; lane = feature.
__global__ __launch_bounds__(256) void pool_kernel(const float* __restrict__ h,
                                                   const int* __restrict__ batch,
                                                   float* __restrict__ psum,
                                                   float* __restrict__ pcnt, int n) {
    int wid  = (blockIdx.x * blockDim.x + threadIdx.x) >> 6;
    int lane = threadIdx.x & 63;
    int beg  = wid * 16;
    if (beg >= n) return;
    int end  = min(beg + 16, n);
    int curb = batch[beg];
    float acc = 0.0f, c = 0.0f;
    for (int i = beg; i < end; ++i) {
        int b = batch[i];  // wave-uniform
        if (b != curb) {
            atomicAdd(&psum[curb * 64 + lane], acc);
            if (lane == 0) atomicAdd(&pcnt[curb], c);
            curb = b; acc = 0.0f; c = 0.0f;
        }
        acc += h[i * 64 + lane];
        c   += 1.0f;
    }
    atomicAdd(&psum[curb * 64 + lane], acc);
    if (lane == 0) atomicAdd(&pcnt[curb], c);
}

__global__ __launch_bounds__(64) void final_kernel(const float* __restrict__ psum,
                                                   const float* __restrict__ pcnt,
                                                   const float* __restrict__ Wl,
                                                   const float* __restrict__ bl,
                                                   float* __restrict__ out, int nb) {
    __shared__ float prow[64];
    int b = blockIdx.x;
    int f = threadIdx.x;
    float c = fmaxf(pcnt[b], 1.0f);
    prow[f] = psum[b * 64 + f] / c;
    __syncthreads();
    if (f < 16) {
        float a = bl[f];
        const float* wr = Wl + f * 64;
#pragma unroll
        for (int k = 0; k < 64; ++k) a += prow[k] * wr[k];
        out[b * 16 + f] = a;
    }
}

extern "C" void kernel_launch(void* const* d_in, const int* in_sizes, int n_in,
                              void* d_out, int out_size, void* d_ws, size_t ws_size,
                              hipStream_t stream) {
    const float* x    = (const float*)d_in[0];
    const int*   ei   = (const int*)d_in[1];
    const int*   batch= (const int*)d_in[2];
    const float* W1   = (const float*)d_in[3];
    const float* b1   = (const float*)d_in[4];
    const float* W2   = (const float*)d_in[5];
    const float* b2   = (const float*)d_in[6];
    const float* W3   = (const float*)d_in[7];
    const float* b3   = (const float*)d_in[8];
    const float* Wl   = (const float*)d_in[9];
    const float* bl   = (const float*)d_in[10];
    float* out = (float*)d_out;

    const int n  = in_sizes[0] / 64;   // 50000 nodes
    const int e  = in_sizes[1] / 2;    // 1250000 edges
    const int nb = out_size / 16;      // 512 graphs

    const int* esrc = ei;
    const int* edst = ei + e;

    char* p = (char*)d_ws;
    auto carve = [&](size_t bytes) {
        char* r = p;
        p += (bytes + 255) & ~(size_t)255;
        return r;
    };
    int*   cnt  = (int*)  carve((size_t)n * 4);          // degree, then fill ctr
    float* dinv = (float*)carve((size_t)n * 4);
    int*   rp   = (int*)  carve((size_t)(n + 1) * 4);
    int*   csr  = (int*)  carve((size_t)e * 4);
    float* bufA = (float*)carve((size_t)n * 64 * 4);
    float* bufB = (float*)carve((size_t)n * 64 * 4);
    float* psum = (float*)carve((size_t)nb * 64 * 4);
    float* pcnt = (float*)carve((size_t)nb * 4);
    int*   bsum = (int*)  carve(((size_t)(n + 1023) / 1024) * 4);

    dim3 blk(256);
    int gN   = (n + 255) / 256;
    int gE   = (e + 255) / 256;
    int nbk  = (n + 1023) / 1024;      // scan blocks

    init_kernel<<<gN, blk, 0, stream>>>(cnt, psum, pcnt, n, nb * 64, nb);
    count_kernel<<<gE, blk, 0, stream>>>(edst, cnt, e);
    scan1_kernel<<<nbk, blk, 0, stream>>>(cnt, bsum, n);
    scan2_kernel<<<1, 64, 0, stream>>>(bsum, rp, nbk, n);
    scan3_kernel<<<nbk, blk, 0, stream>>>(cnt, bsum, rp, dinv, n);
    fill_kernel<<<gE, blk, 0, stream>>>(esrc, edst, rp, cnt, csr, e);

    int gMM  = (n + 63) / 64;
    int gAGG = (n + 3) / 4;  // 4 waves/block, one node per wave
    int gPL  = ((n + 15) / 16 + 3) / 4;

    mm_kernel<<<gMM, blk, 0, stream>>>(x, W1, dinv, bufA, n);
    agg_kernel<<<gAGG, blk, 0, stream>>>(bufA, rp, csr, dinv, b1, bufB, n);
    mm_kernel<<<gMM, blk, 0, stream>>>(bufB, W2, dinv, bufA, n);
    agg_kernel<<<gAGG, blk, 0, stream>>>(bufA, rp, csr, dinv, b2, bufB, n);
    mm_kernel<<<gMM, blk, 0, stream>>>(bufB, W3, dinv, bufA, n);
    agg_kernel<<<gAGG, blk, 0, stream>>>(bufA, rp, csr, dinv, b3, bufB, n);

    pool_kernel<<<gPL, blk, 0, stream>>>(bufB, batch, psum, pcnt, n);
    final_kernel<<<nb, 64, 0, stream>>>(psum, pcnt, Wl, bl, out, nb);
}

// Round 3
// 442.710 us; speedup vs baseline: 1.4776x; 1.0719x over previous
//
#include <hip/hip_runtime.h>

// ---------------------------------------------------------------------------
// GCN (3 layers) + global mean pool + linear, fp32, MI355X.
// norm = dinv[src]*dinv[dst] factors -> fold dinv into matmul output
// (t'[i] = dinv[i] * h[i] W^T); aggregation is a pure unweighted CSR sum:
//   h_next[i] = relu(dinv[i]*(t'[i] + sum_{j->i} t'[j]) + b)
// R2: parallel 3-phase scan, dinv fused into scan3, segment-aware pooling.
// R3: XCD-partitioned fill (blockIdx&7 = dst range) to kill the 16x write
//     amplification (84MB -> ~8MB); agg gather unrolled 8-way.
// ---------------------------------------------------------------------------

__global__ __launch_bounds__(256) void init_kernel(int* __restrict__ cnt,
                                                   float* __restrict__ psum,
                                                   float* __restrict__ pcnt,
                                                   int n, int pb64, int pb) {
    int idx = blockIdx.x * blockDim.x + threadIdx.x;
    if (idx < n)    cnt[idx]  = 0;
    if (idx < pb64) psum[idx] = 0.0f;
    if (idx < pb)   pcnt[idx] = 0.0f;
}

__global__ __launch_bounds__(256) void count_kernel(const int* __restrict__ dst,
                                                    int* __restrict__ cnt, int e) {
    int idx = blockIdx.x * blockDim.x + threadIdx.x;
    if (idx < e) atomicAdd(&cnt[dst[idx]], 1);
}

// ---- 3-phase exclusive scan of cnt[0..n) -> rp, 1024 elements per block ----

__global__ __launch_bounds__(256) void scan1_kernel(const int* __restrict__ cnt,
                                                    int* __restrict__ bsum, int n) {
    int base = blockIdx.x * 1024;
    int tid  = threadIdx.x;
    int s = 0;
#pragma unroll
    for (int k = 0; k < 4; ++k) {
        int i = base + tid + k * 256;  // coalesced
        if (i < n) s += cnt[i];
    }
    for (int d = 32; d >= 1; d >>= 1) s += __shfl_down(s, d, 64);
    __shared__ int ws[4];
    if ((tid & 63) == 0) ws[tid >> 6] = s;
    __syncthreads();
    if (tid == 0) bsum[blockIdx.x] = ws[0] + ws[1] + ws[2] + ws[3];
}

// Single wave: exclusive scan of bsum[0..nbk), writes total to rp[n].
__global__ __launch_bounds__(64) void scan2_kernel(int* __restrict__ bsum,
                                                   int* __restrict__ rp,
                                                   int nbk, int n) {
    int tid = threadIdx.x;
    int carry = 0;
    for (int b0 = 0; b0 < nbk; b0 += 64) {
        int idx  = b0 + tid;
        int v    = (idx < nbk) ? bsum[idx] : 0;
        int orig = v;
        for (int d = 1; d < 64; d <<= 1) {
            int t = __shfl_up(v, d, 64);
            if (tid >= d) v += t;
        }
        if (idx < nbk) bsum[idx] = carry + v - orig;  // exclusive
        carry += __shfl(v, 63, 64);
    }
    if (tid == 0) rp[n] = carry;
}

// Per-block rescan with block offset; also computes dinv and zeroes cnt.
__global__ __launch_bounds__(256) void scan3_kernel(int* __restrict__ cnt,
                                                    const int* __restrict__ bsum,
                                                    int* __restrict__ rp,
                                                    float* __restrict__ dinv, int n) {
    int tid  = threadIdx.x;
    int lane = tid & 63;
    int wv   = tid >> 6;
    int i0   = blockIdx.x * 1024 + tid * 4;

    int4 c = make_int4(0, 0, 0, 0);
    if (i0 + 3 < n) {
        c = *(const int4*)(cnt + i0);
    } else {
        if (i0 + 0 < n) c.x = cnt[i0 + 0];
        if (i0 + 1 < n) c.y = cnt[i0 + 1];
        if (i0 + 2 < n) c.z = cnt[i0 + 2];
        if (i0 + 3 < n) c.w = cnt[i0 + 3];
    }
    int tsum = c.x + c.y + c.z + c.w;
    int v = tsum;
    for (int d = 1; d < 64; d <<= 1) {
        int t = __shfl_up(v, d, 64);
        if (lane >= d) v += t;
    }
    __shared__ int wsum[4];
    if (lane == 63) wsum[wv] = v;
    __syncthreads();
    int woff = 0;
    for (int w = 0; w < wv; ++w) woff += wsum[w];

    int p0 = bsum[blockIdx.x] + woff + (v - tsum);
    int p1 = p0 + c.x;
    int p2 = p1 + c.y;
    int p3 = p2 + c.z;
    if (i0 + 3 < n) {
        *(int4*)(rp + i0) = make_int4(p0, p1, p2, p3);
        *(float4*)(dinv + i0) =
            make_float4(rsqrtf((float)(c.x + 1)), rsqrtf((float)(c.y + 1)),
                        rsqrtf((float)(c.z + 1)), rsqrtf((float)(c.w + 1)));
        *(int4*)(cnt + i0) = make_int4(0, 0, 0, 0);
    } else {
        if (i0 + 0 < n) { rp[i0+0]=p0; dinv[i0+0]=rsqrtf((float)(c.x+1)); cnt[i0+0]=0; }
        if (i0 + 1 < n) { rp[i0+1]=p1; dinv[i0+1]=rsqrtf((float)(c.y+1)); cnt[i0+1]=0; }
        if (i0 + 2 < n) { rp[i0+2]=p2; dinv[i0+2]=rsqrtf((float)(c.z+1)); cnt[i0+2]=0; }
        if (i0 + 3 < n) { rp[i0+3]=p3; dinv[i0+3]=rsqrtf((float)(c.w+1)); cnt[i0+3]=0; }
    }
}

// XCD-partitioned CSR fill: blockIdx&7 selects a dst range; with round-robin
// block->XCD dispatch each 640KB csr slice is written by one XCD's L2 so the
// scattered 4B stores write-combine (was 84MB of HBM writes, 16x amplified).
__global__ __launch_bounds__(256) void fill_kernel(const int* __restrict__ src,
                                                   const int* __restrict__ dst,
                                                   const int* __restrict__ rp,
                                                   int* __restrict__ fill,
                                                   int* __restrict__ csr,
                                                   int e, int n) {
    int range = blockIdx.x & 7;
    int chunk = blockIdx.x >> 3;
    int lo = (int)(((long long)n * range) >> 3);
    int hi = (int)(((long long)n * (range + 1)) >> 3);
    int base = chunk * 1024;
#pragma unroll
    for (int k = 0; k < 4; ++k) {
        int idx = base + threadIdx.x + k * 256;  // coalesced
        if (idx < e) {
            int d = dst[idx];
            if (d >= lo && d < hi) {
                int pos = rp[d] + atomicAdd(&fill[d], 1);
                csr[pos] = src[idx];
            }
        }
    }
}

// t[i][o] = dinv[i] * sum_k h[i][k] * W[o][k]
// 256 thr = 4 waves; 64 nodes/block. W row per lane in 16 float4 regs;
// 64 h-rows staged in LDS, read as broadcast float4.
__global__ __launch_bounds__(256) void mm_kernel(const float* __restrict__ h,
                                                 const float* __restrict__ W,
                                                 const float* __restrict__ dinv,
                                                 float* __restrict__ t, int n) {
    __shared__ float hs[64 * 64];
    int tid  = threadIdx.x;
    int lane = tid & 63;
    int wave = tid >> 6;
    int base = blockIdx.x * 64;

    float4 wreg[16];
    const float4* W4 = (const float4*)(W + lane * 64);
#pragma unroll
    for (int q = 0; q < 16; ++q) wreg[q] = W4[q];

    int nrows = min(64, n - base);
    const float4* h4  = (const float4*)(h + (size_t)base * 64);
    float4*       hs4 = (float4*)hs;
    for (int idx = tid; idx < nrows * 16; idx += 256) hs4[idx] = h4[idx];
    __syncthreads();

    for (int r = wave * 16; r < wave * 16 + 16; ++r) {
        int i = base + r;
        if (i >= n) break;
        const float4* row = (const float4*)(hs + r * 64);
        float acc = 0.0f;
#pragma unroll
        for (int q = 0; q < 16; ++q) {
            float4 hv = row[q];  // wave-uniform address -> LDS broadcast
            acc += hv.x * wreg[q].x + hv.y * wreg[q].y +
                   hv.z * wreg[q].z + hv.w * wreg[q].w;
        }
        t[i * 64 + lane] = acc * dinv[i];
    }
}

// One wave per node; lane = feature. 8-way unrolled gather-sum over in-edges
// (more loads in flight to hide L2/L3 gather latency).
__global__ __launch_bounds__(256) void agg_kernel(const float* __restrict__ t,
                                                  const int* __restrict__ rp,
                                                  const int* __restrict__ cs,
                                                  const float* __restrict__ dinv,
                                                  const float* __restrict__ bias,
                                                  float* __restrict__ hout, int n) {
    int gw   = (blockIdx.x * blockDim.x + threadIdx.x) >> 6;
    int lane = threadIdx.x & 63;
    if (gw >= n) return;
    int i   = gw;
    int beg = rp[i];
    int end = rp[i + 1];
    float acc0 = t[i * 64 + lane];  // self loop
    float acc1 = 0.f, acc2 = 0.f, acc3 = 0.f;
    float acc4 = 0.f, acc5 = 0.f, acc6 = 0.f, acc7 = 0.f;
    int e = beg;
    for (; e + 8 <= end; e += 8) {
        int s0 = cs[e],     s1 = cs[e + 1], s2 = cs[e + 2], s3 = cs[e + 3];
        int s4 = cs[e + 4], s5 = cs[e + 5], s6 = cs[e + 6], s7 = cs[e + 7];
        acc0 += t[s0 * 64 + lane];
        acc1 += t[s1 * 64 + lane];
        acc2 += t[s2 * 64 + lane];
        acc3 += t[s3 * 64 + lane];
        acc4 += t[s4 * 64 + lane];
        acc5 += t[s5 * 64 + lane];
        acc6 += t[s6 * 64 + lane];
        acc7 += t[s7 * 64 + lane];
    }
    for (; e < end; ++e) acc1 += t[cs[e] * 64 + lane];
    float acc = ((acc0 + acc1) + (acc2 + acc3)) + ((acc4 + acc5) + (acc6 + acc7));
    hout[i * 64 + lane] = fmaxf(fmaf(dinv[i], acc, bias[lane]), 0.0f);
}

// Sorted batch -> segment accumulate in registers, flush atomics on change.
// One wave handles 16 consecutive nodes; lane = feature.
__global__ __launch_bounds__(256) void pool_kernel(const float* __restrict__ h,
                                                   const int* __restrict__ batch,
                                                   float* __restrict__ psum,
                                                   float* __restrict__ pcnt, int n) {
    int wid  = (blockIdx.x * blockDim.x + threadIdx.x) >> 6;
    int lane = threadIdx.x & 63;
    int beg  = wid * 16;
    if (beg >= n) return;
    int end  = min(beg + 16, n);
    int curb = batch[beg];
    float acc = 0.0f, c = 0.0f;
    for (int i = beg; i < end; ++i) {
        int b = batch[i];  // wave-uniform
        if (b != curb) {
            atomicAdd(&psum[curb * 64 + lane], acc);
            if (lane == 0) atomicAdd(&pcnt[curb], c);
            curb = b; acc = 0.0f; c = 0.0f;
        }
        acc += h[i * 64 + lane];
        c   += 1.0f;
    }
    atomicAdd(&psum[curb * 64 + lane], acc);
    if (lane == 0) atomicAdd(&pcnt[curb], c);
}

__global__ __launch_bounds__(64) void final_kernel(const float* __restrict__ psum,
                                                   const float* __restrict__ pcnt,
                                                   const float* __restrict__ Wl,
                                                   const float* __restrict__ bl,
                                                   float* __restrict__ out, int nb) {
    __shared__ float prow[64];
    int b = blockIdx.x;
    int f = threadIdx.x;
    float c = fmaxf(pcnt[b], 1.0f);
    prow[f] = psum[b * 64 + f] / c;
    __syncthreads();
    if (f < 16) {
        float a = bl[f];
        const float* wr = Wl + f * 64;
#pragma unroll
        for (int k = 0; k < 64; ++k) a += prow[k] * wr[k];
        out[b * 16 + f] = a;
    }
}

extern "C" void kernel_launch(void* const* d_in, const int* in_sizes, int n_in,
                              void* d_out, int out_size, void* d_ws, size_t ws_size,
                              hipStream_t stream) {
    const float* x    = (const float*)d_in[0];
    const int*   ei   = (const int*)d_in[1];
    const int*   batch= (const int*)d_in[2];
    const float* W1   = (const float*)d_in[3];
    const float* b1   = (const float*)d_in[4];
    const float* W2   = (const float*)d_in[5];
    const float* b2   = (const float*)d_in[6];
    const float* W3   = (const float*)d_in[7];
    const float* b3   = (const float*)d_in[8];
    const float* Wl   = (const float*)d_in[9];
    const float* bl   = (const float*)d_in[10];
    float* out = (float*)d_out;

    const int n  = in_sizes[0] / 64;   // 50000 nodes
    const int e  = in_sizes[1] / 2;    // 1250000 edges
    const int nb = out_size / 16;      // 512 graphs

    const int* esrc = ei;
    const int* edst = ei + e;

    char* p = (char*)d_ws;
    auto carve = [&](size_t bytes) {
        char* r = p;
        p += (bytes + 255) & ~(size_t)255;
        return r;
    };
    int*   cnt  = (int*)  carve((size_t)n * 4);          // degree, then fill ctr
    float* dinv = (float*)carve((size_t)n * 4);
    int*   rp   = (int*)  carve((size_t)(n + 1) * 4);
    int*   csr  = (int*)  carve((size_t)e * 4);
    float* bufA = (float*)carve((size_t)n * 64 * 4);
    float* bufB = (float*)carve((size_t)n * 64 * 4);
    float* psum = (float*)carve((size_t)nb * 64 * 4);
    float* pcnt = (float*)carve((size_t)nb * 4);
    int*   bsum = (int*)  carve(((size_t)(n + 1023) / 1024) * 4);

    dim3 blk(256);
    int gN   = (n + 255) / 256;
    int gE   = (e + 255) / 256;
    int nbk  = (n + 1023) / 1024;      // scan blocks
    int gFI  = ((e + 1023) / 1024) * 8;  // chunks x 8 dst-ranges

    init_kernel<<<gN, blk, 0, stream>>>(cnt, psum, pcnt, n, nb * 64, nb);
    count_kernel<<<gE, blk, 0, stream>>>(edst, cnt, e);
    scan1_kernel<<<nbk, blk, 0, stream>>>(cnt, bsum, n);
    scan2_kernel<<<1, 64, 0, stream>>>(bsum, rp, nbk, n);
    scan3_kernel<<<nbk, blk, 0, stream>>>(cnt, bsum, rp, dinv, n);
    fill_kernel<<<gFI, blk, 0, stream>>>(esrc, edst, rp, cnt, csr, e, n);

    int gMM  = (n + 63) / 64;
    int gAGG = (n + 3) / 4;  // 4 waves/block, one node per wave
    int gPL  = ((n + 15) / 16 + 3) / 4;

    mm_kernel<<<gMM, blk, 0, stream>>>(x, W1, dinv, bufA, n);
    agg_kernel<<<gAGG, blk, 0, stream>>>(bufA, rp, csr, dinv, b1, bufB, n);
    mm_kernel<<<gMM, blk, 0, stream>>>(bufB, W2, dinv, bufA, n);
    agg_kernel<<<gAGG, blk, 0, stream>>>(bufA, rp, csr, dinv, b2, bufB, n);
    mm_kernel<<<gMM, blk, 0, stream>>>(bufB, W3, dinv, bufA, n);
    agg_kernel<<<gAGG, blk, 0, stream>>>(bufA, rp, csr, dinv, b3, bufB, n);

    pool_kernel<<<gPL, blk, 0, stream>>>(bufB, batch, psum, pcnt, n);
    final_kernel<<<nb, 64, 0, stream>>>(psum, pcnt, Wl, bl, out, nb);
}